// Round 5
// baseline (201.649 us; speedup 1.0000x reference)
//
#include <hip/hip_runtime.h>
#include <hip/hip_cooperative_groups.h>

namespace cg = cooperative_groups;

// Fused MaskLoss, cooperative with gated fallback.
//   A: gray(u16) + 2048-bin LDS hist -> per-block sub-hist, per-block min/max
//   B: (128 blocks) merge 4 sub-hists into register bins; 20 Lloyd iters,
//      each a block reduction of (count,sum) above threshold (interp model)
//   C: dual MSE (flip=0/1) + border counts (gray from regs in coop path,
//      from u16 cache in fallback)
//   D: border vote + final reduce -> out
// No ws init required: every word read was written earlier the same call.

constexpr int NB   = 2048;
constexpr int NPIX = 65536;
constexpr int KM_ITERS = 20;
constexpr int GRID = 512, TPB = 256, BPI = 4;   // 4 blocks/image
constexpr int PXB  = 16384;                     // px per block (64/thread)
constexpr float QINV = 1.0f / 65536.0f;
constexpr float BINW = 1.0f / 2048.0f;

constexpr size_t OFF_BMM   = 0;                         // 512 uint2 {min,max}
constexpr size_t OFF_TINFO = 4096;                      // 128 float4 {t,hi,0,0}
constexpr size_t OFF_BSUM  = 8192;                      // 512 float2 {mse0,mse1}
constexpr size_t OFF_BBORD = 16384;                     // 512 float4 borders
constexpr size_t OFF_SUBH  = 32768;                     // 512*2048 u32 (4 MB)
constexpr size_t OFF_GRAY  = OFF_SUBH + (size_t)GRID * NB * 4;  // 16.8 MB (fallback)

struct ShA { unsigned hc[NB]; unsigned mn[4]; unsigned mx[4]; };
struct ShB { float w1[4]; float w2[4]; };
struct ShC { float a0[4]; float a1[4]; float4 bd[4]; };
struct ShD { float flip[128]; float sm[4]; };
union ShU { ShA a; ShB b; ShC c; ShD d; };

__device__ __forceinline__ float waveSumF(float v) {
#pragma unroll
    for (int off = 32; off > 0; off >>= 1) v += __shfl_down(v, off, 64);
    return v;
}
__device__ __forceinline__ unsigned waveMinU(unsigned v) {
#pragma unroll
    for (int off = 32; off > 0; off >>= 1) v = min(v, (unsigned)__shfl_down((int)v, off, 64));
    return v;
}
__device__ __forceinline__ unsigned waveMaxU(unsigned v) {
#pragma unroll
    for (int off = 32; off > 0; off >>= 1) v = max(v, (unsigned)__shfl_down((int)v, off, 64));
    return v;
}

// ---------------- phase A ----------------
template<bool COOP>
__device__ __forceinline__ void phaseA(int bid, int tid, const float* __restrict__ hr,
        uint2* __restrict__ bmm, unsigned* __restrict__ subh,
        ushort* __restrict__ gray, unsigned* g16, ShA& sh) {
    const int img = bid >> 2, part = bid & 3, lane = tid & 63, wid = tid >> 6;
    for (int j = tid; j < NB; j += TPB) sh.hc[j] = 0u;
    __syncthreads();
    const float* r = hr + (size_t)img * 3 * NPIX;
    const float* g = r + NPIX;
    const float* b = g + NPIX;
    ushort* gp = gray ? (gray + (size_t)img * NPIX) : nullptr;
    unsigned umn = 65535u, umx = 0u;
#pragma unroll
    for (int i = 0; i < 16; ++i) {
        const int p = part * PXB + i * 1024 + tid * 4;
        float4 rr = *(const float4*)(r + p);
        float4 gg = *(const float4*)(g + p);
        float4 bb = *(const float4*)(b + p);
        float x[4] = { (rr.x + gg.x + bb.x) * (1.0f / 3.0f),
                       (rr.y + gg.y + bb.y) * (1.0f / 3.0f),
                       (rr.z + gg.z + bb.z) * (1.0f / 3.0f),
                       (rr.w + gg.w + bb.w) * (1.0f / 3.0f) };
        unsigned u[4];
#pragma unroll
        for (int j = 0; j < 4; ++j) {
            unsigned uu = (unsigned)(x[j] * 65536.0f);
            uu = min(uu, 65535u);
            u[j] = uu;
            umn = min(umn, uu); umx = max(umx, uu);
            atomicAdd(&sh.hc[uu >> 5], 1u);
        }
        if constexpr (COOP) {
            g16[2 * i]     = u[0] | (u[1] << 16);
            g16[2 * i + 1] = u[2] | (u[3] << 16);
        } else {
            ushort4 u4;
            u4.x = (ushort)u[0]; u4.y = (ushort)u[1];
            u4.z = (ushort)u[2]; u4.w = (ushort)u[3];
            *(ushort4*)(gp + p) = u4;
        }
    }
    umn = waveMinU(umn); umx = waveMaxU(umx);
    if (lane == 0) { sh.mn[wid] = umn; sh.mx[wid] = umx; }
    __syncthreads();
    if (tid == 0) {
        bmm[bid] = make_uint2(min(min(sh.mn[0], sh.mn[1]), min(sh.mn[2], sh.mn[3])),
                              max(max(sh.mx[0], sh.mx[1]), max(sh.mx[2], sh.mx[3])));
    }
    unsigned* ho = subh + (size_t)bid * NB;
    for (int j = tid; j < NB; j += TPB) ho[j] = sh.hc[j];
}

// ---------------- phase B ----------------
__device__ __forceinline__ void phaseB(int img, int tid, const uint2* __restrict__ bmm,
        const unsigned* __restrict__ subh, float4* __restrict__ tinfo, ShB& sh) {
    const int lane = tid & 63, wid = tid >> 6, base = tid * 8;
    float n8[8], c8[8];
#pragma unroll
    for (int u = 0; u < 8; ++u) {
        const unsigned* hp = subh + (size_t)(img * BPI) * NB + (base + u);
        const unsigned c = hp[0] + hp[NB] + hp[2 * NB] + hp[3 * NB];
        n8[u] = (float)c;
        c8[u] = ((float)(base + u) + 0.484375f) * BINW;   // mean u16 code in bin
    }
    float pS = 0.0f;
#pragma unroll
    for (int u = 0; u < 8; ++u) pS += n8[u] * c8[u];
    pS = waveSumF(pS);
    if (lane == 0) sh.w1[wid] = pS;
    __syncthreads();
    const float Stot = sh.w1[0] + sh.w1[1] + sh.w1[2] + sh.w1[3];
    const float Ntot = (float)NPIX;
    const uint2 m0 = bmm[img * BPI], m1 = bmm[img * BPI + 1],
                m2 = bmm[img * BPI + 2], m3 = bmm[img * BPI + 3];
    float c0 = (float)min(min(m0.x, m1.x), min(m2.x, m3.x)) * QINV;
    float c1 = (float)max(max(m0.y, m1.y), max(m2.y, m3.y)) * QINV;
    __syncthreads();
#pragma unroll 1
    for (int it = 0; it < KM_ITERS; ++it) {
        const float t = 0.5f * (c0 + c1);
        float aN = 0.0f, aS = 0.0f;
        if (c1 != c0) {
#pragma unroll
            for (int u = 0; u < 8; ++u) {
                const float bs = (float)(base + u) * BINW, be = bs + BINW;
                if (t <= bs) { aN += n8[u]; aS += n8[u] * c8[u]; }
                else if (t < be) {
                    const float fr = (be - t) * (float)NB;          // in (0,1]
                    aN += n8[u] * fr;
                    aS += n8[u] * fr * 0.5f * (t + be);             // uniform in-bin
                }
            }
        }
        aN = waveSumF(aN); aS = waveSumF(aS);
        if (lane == 0) { sh.w1[wid] = aN; sh.w2[wid] = aS; }
        __syncthreads();
        const float AN = sh.w1[0] + sh.w1[1] + sh.w1[2] + sh.w1[3];
        const float AS = sh.w2[0] + sh.w2[1] + sh.w2[2] + sh.w2[3];
        float n1, s1;
        if (c1 == c0)      { n1 = 0.0f;       s1 = 0.0f; }
        else if (c1 > c0)  { n1 = AN;         s1 = AS; }
        else               { n1 = Ntot - AN;  s1 = Stot - AS; }
        const float c1n = s1 / fmaxf(n1, 1.0f);
        const float c0n = (Stot - s1) / fmaxf(Ntot - n1, 1.0f);
        __syncthreads();                      // protect w1/w2 reuse next iter
        if (c1n == c1 && c0n == c0) break;    // uniform: same FP math every thread
        c0 = c0n; c1 = c1n;
    }
    if (tid == 0) {
        float tf, hii;
        if (c1 == c0) { tf = -1e30f; hii = 0.0f; }   // lo-mode, never true -> all 0
        else { tf = 0.5f * (c0 + c1); hii = (c1 > c0) ? 1.0f : 0.0f; }
        tinfo[img] = make_float4(tf, hii, 0.0f, 0.0f);
    }
}

// ---------------- phase C ----------------
template<bool COOP>
__device__ __forceinline__ void phaseC(int bid, int tid, const unsigned* g16,
        const ushort* __restrict__ gray, const float* __restrict__ sr,
        const float4* __restrict__ tinfo, float2* __restrict__ bsum,
        float4* __restrict__ bbord, ShC& sh) {
    const int img = bid >> 2, part = bid & 3, lane = tid & 63, wid = tid >> 6;
    const float4 ti = tinfo[img];
    const float t = ti.x;
    const bool hi = (ti.y != 0.0f);
    const float* sp = sr + (size_t)img * NPIX;
    const ushort* gp = gray ? (gray + (size_t)img * NPIX) : nullptr;
    float a0 = 0.0f, a1 = 0.0f, frr = 0.0f, lrr = 0.0f, fcc = 0.0f, lcc = 0.0f;
#pragma unroll
    for (int i = 0; i < 16; ++i) {
        const int p = part * PXB + i * 1024 + tid * 4;
        float4 ss = *(const float4*)(sp + p);
        unsigned uu[4];
        if constexpr (COOP) {
            uu[0] = g16[2 * i] & 0xFFFFu;     uu[1] = g16[2 * i] >> 16;
            uu[2] = g16[2 * i + 1] & 0xFFFFu; uu[3] = g16[2 * i + 1] >> 16;
        } else {
            ushort4 u4 = *(const ushort4*)(gp + p);
            uu[0] = u4.x; uu[1] = u4.y; uu[2] = u4.z; uu[3] = u4.w;
        }
        const int row = p >> 8;
        const float sv[4] = { ss.x, ss.y, ss.z, ss.w };
#pragma unroll
        for (int j = 0; j < 4; ++j) {
            const float x = (float)uu[j] * QINV;
            const bool one = hi ? (x > t) : (x < t);
            const float m = one ? 1.0f : 0.0f;
            const float d0 = sv[j] - m;
            const float d1 = sv[j] - (1.0f - m);
            a0 += d0 * d0;
            a1 += d1 * d1;
            const int col = (p & 255) + j;
            if (col == 0)   fcc += m;
            if (col == 255) lcc += m;
            if (row == 0)   frr += m;
            if (row == 255) lrr += m;
        }
    }
    a0 = waveSumF(a0); a1 = waveSumF(a1);
    frr = waveSumF(frr); lrr = waveSumF(lrr);
    fcc = waveSumF(fcc); lcc = waveSumF(lcc);
    if (lane == 0) {
        sh.a0[wid] = a0; sh.a1[wid] = a1;
        sh.bd[wid] = make_float4(frr, lrr, fcc, lcc);
    }
    __syncthreads();
    if (tid == 0) {
        bsum[bid] = make_float2(sh.a0[0] + sh.a0[1] + sh.a0[2] + sh.a0[3],
                                sh.a1[0] + sh.a1[1] + sh.a1[2] + sh.a1[3]);
        bbord[bid] = make_float4(sh.bd[0].x + sh.bd[1].x + sh.bd[2].x + sh.bd[3].x,
                                 sh.bd[0].y + sh.bd[1].y + sh.bd[2].y + sh.bd[3].y,
                                 sh.bd[0].z + sh.bd[1].z + sh.bd[2].z + sh.bd[3].z,
                                 sh.bd[0].w + sh.bd[1].w + sh.bd[2].w + sh.bd[3].w);
    }
}

// ---------------- phase D ----------------
__device__ __forceinline__ void phaseD(int tid, const float2* __restrict__ bsum,
        const float4* __restrict__ bbord, float* __restrict__ out, ShD& sh) {
    const int lane = tid & 63, wid = tid >> 6;
    if (tid < 128) {
        float FR = 0.0f, LR = 0.0f, FC = 0.0f, LC = 0.0f;
#pragma unroll
        for (int q = 0; q < 4; ++q) {
            const float4 v = bbord[tid * 4 + q];
            FR += v.x; LR += v.y; FC += v.z; LC += v.w;
        }
        const int num = (FR > 128.0f) + (LR > 128.0f) + (FC > 128.0f) + (LC > 128.0f);
        sh.flip[tid] = (num >= 3) ? 1.0f : 0.0f;
    }
    __syncthreads();
    float acc = 0.0f;
#pragma unroll
    for (int q = 0; q < 2; ++q) {
        const int e = tid * 2 + q;
        const float2 v = bsum[e];
        acc += (sh.flip[e >> 2] != 0.0f) ? v.y : v.x;
    }
    acc = waveSumF(acc);
    if (lane == 0) sh.sm[wid] = acc;
    __syncthreads();
    if (tid == 0)
        out[0] = (sh.sm[0] + sh.sm[1] + sh.sm[2] + sh.sm[3]) * (1.0f / 8388608.0f);
}

// ---------------- cooperative fused kernel ----------------
__global__ __launch_bounds__(TPB) void coop_maskloss(
        const float* __restrict__ hr, const float* __restrict__ sr,
        uint2* __restrict__ bmm, unsigned* __restrict__ subh,
        float4* __restrict__ tinfo, float2* __restrict__ bsum,
        float4* __restrict__ bbord, float* __restrict__ out) {
    __shared__ ShU sh;
    const int bid = blockIdx.x, tid = threadIdx.x;
    unsigned g16[32];
    cg::grid_group grid = cg::this_grid();
    phaseA<true>(bid, tid, hr, bmm, subh, nullptr, g16, sh.a);
    grid.sync();
    if (bid < 128) phaseB(bid, tid, bmm, subh, tinfo, sh.b);
    grid.sync();
    phaseC<true>(bid, tid, g16, nullptr, sr, tinfo, bsum, bbord, sh.c);
    grid.sync();
    if (bid == 0) phaseD(tid, bsum, bbord, out, sh.d);
}

// ---------------- fallback kernels ----------------
__global__ __launch_bounds__(TPB) void fbA(const float* __restrict__ hr,
        uint2* __restrict__ bmm, unsigned* __restrict__ subh,
        ushort* __restrict__ gray) {
    __shared__ ShA sh;
    phaseA<false>(blockIdx.x, threadIdx.x, hr, bmm, subh, gray, nullptr, sh);
}
__global__ __launch_bounds__(TPB) void fbB(const uint2* __restrict__ bmm,
        const unsigned* __restrict__ subh, float4* __restrict__ tinfo) {
    __shared__ ShB sh;
    phaseB(blockIdx.x, threadIdx.x, bmm, subh, tinfo, sh);
}
__global__ __launch_bounds__(TPB) void fbC(const ushort* __restrict__ gray,
        const float* __restrict__ sr, const float4* __restrict__ tinfo,
        float2* __restrict__ bsum, float4* __restrict__ bbord) {
    __shared__ ShC sh;
    phaseC<false>(blockIdx.x, threadIdx.x, nullptr, gray, sr, tinfo, bsum, bbord, sh);
}
__global__ __launch_bounds__(TPB) void fbD(const float2* __restrict__ bsum,
        const float4* __restrict__ bbord, float* __restrict__ out) {
    __shared__ ShD sh;
    phaseD(threadIdx.x, bsum, bbord, out, sh);
}

extern "C" void kernel_launch(void* const* d_in, const int* in_sizes, int n_in,
                              void* d_out, int out_size, void* d_ws, size_t ws_size,
                              hipStream_t stream) {
    const float* hr = (const float*)d_in[0];   // [128,3,256,256] f32
    const float* sr = (const float*)d_in[1];   // [128,1,256,256] f32
    float* out = (float*)d_out;

    char* ws = (char*)d_ws;
    uint2*    bmm   = (uint2*)(ws + OFF_BMM);
    float4*   tinfo = (float4*)(ws + OFF_TINFO);
    float2*   bsum  = (float2*)(ws + OFF_BSUM);
    float4*   bbord = (float4*)(ws + OFF_BBORD);
    unsigned* subh  = (unsigned*)(ws + OFF_SUBH);
    ushort*   gray  = (ushort*)(ws + OFF_GRAY);

    // Host-side gate (capture-safe: pure host queries, no stream ops).
    int dev = 0; hipGetDevice(&dev);
    int coopAttr = 0;
    hipDeviceGetAttribute(&coopAttr, hipDeviceAttributeCooperativeLaunch, dev);
    int numCU = 0;
    hipDeviceGetAttribute(&numCU, hipDeviceAttributeMultiprocessorCount, dev);
    int maxb = 0;
    hipError_t eOcc = hipOccupancyMaxActiveBlocksPerMultiprocessor(
        &maxb, coop_maskloss, TPB, 0);
    const bool tryCoop = (coopAttr != 0) && (eOcc == hipSuccess) &&
                         ((long)maxb * (long)numCU >= (long)GRID);

    bool done = false;
    if (tryCoop) {
        void* args[] = { (void*)&hr, (void*)&sr, (void*)&bmm, (void*)&subh,
                         (void*)&tinfo, (void*)&bsum, (void*)&bbord, (void*)&out };
        hipError_t e = hipLaunchCooperativeKernel(coop_maskloss, dim3(GRID),
                                                  dim3(TPB), args, 0, stream);
        done = (e == hipSuccess);
    }
    if (!done) {
        fbA<<<GRID, TPB, 0, stream>>>(hr, bmm, subh, gray);
        fbB<<<128,  TPB, 0, stream>>>(bmm, subh, tinfo);
        fbC<<<GRID, TPB, 0, stream>>>(gray, sr, tinfo, bsum, bbord);
        fbD<<<1,    TPB, 0, stream>>>(bsum, bbord, out);
    }
}